// Round 2
// baseline (243.676 us; speedup 1.0000x reference)
//
#include <hip/hip_runtime.h>
#include <hip/hip_bf16.h>
#include <math.h>

#define NB 4096        // batch
#define ED 1024        // embed dim
#define RT_TILES 32    // 4096/128
#define CT_TILES 64    // 8192/128
#define CHUNKS   128   // 8192/64 : one partial per 64-col chunk (per wave-col)

typedef __attribute__((ext_vector_type(8))) short bf16x8;
typedef __attribute__((ext_vector_type(4))) float f32x4;

__device__ inline unsigned short f2bf(float x) {
    unsigned u = __builtin_bit_cast(unsigned, x);
    unsigned r = (u + 0x7fffu + ((u >> 16) & 1u)) >> 16;
    return (unsigned short)r;
}

// ---------- Kernel 1: L2-normalize rows, cast to bf16 ----------
__global__ __launch_bounds__(256) void normalize_cast(
    const float* __restrict__ q, const float* __restrict__ p,
    const float* __restrict__ n,
    unsigned short* __restrict__ Abf, unsigned short* __restrict__ Bbf)
{
    const int bid = blockIdx.x;
    const int mat = bid >> 12;          // 0:q 1:p 2:n
    const int row = bid & 4095;
    const float* src = (mat == 0) ? q : (mat == 1 ? p : n);
    unsigned short* dst = (mat == 0)
        ? (Abf + (size_t)row * ED)
        : (Bbf + ((size_t)(mat - 1) * NB + row) * ED);

    const int t = threadIdx.x;
    const float4 v = *(const float4*)(src + (size_t)row * ED + t * 4);
    float ss = v.x * v.x + v.y * v.y + v.z * v.z + v.w * v.w;
    #pragma unroll
    for (int off = 32; off > 0; off >>= 1) ss += __shfl_down(ss, off, 64);

    __shared__ float wsum[4];
    __shared__ float inv_s;
    const int wv = t >> 6, ln = t & 63;
    if (ln == 0) wsum[wv] = ss;
    __syncthreads();
    if (t == 0) {
        float nrm = sqrtf(wsum[0] + wsum[1] + wsum[2] + wsum[3]);
        inv_s = 1.0f / fmaxf(nrm, 1e-12f);
    }
    __syncthreads();
    const float inv = inv_s;
    ushort4 o;
    o.x = f2bf(v.x * inv);
    o.y = f2bf(v.y * inv);
    o.z = f2bf(v.z * inv);
    o.w = f2bf(v.w * inv);
    *(ushort4*)(dst + t * 4) = o;
}

// ---------- Kernel 2: 128x128 tile bf16 MFMA GEMM with fused per-64-col-chunk
// row max / sum-exp partials + diagonal extraction ----------
// grid (64 col-tiles, 32 row-tiles), 256 threads (4 waves, 2x2 of 64x64).
__global__ __launch_bounds__(256) void gemm_softmax_partial(
    const unsigned short* __restrict__ Abf, const unsigned short* __restrict__ Bbf,
    float* __restrict__ part_m, float* __restrict__ part_s,
    float* __restrict__ diag)
{
    __shared__ unsigned short As[128 * 64];
    __shared__ unsigned short Bs[128 * 64];

    const int ct = blockIdx.x;   // 0..63
    const int rt = blockIdx.y;   // 0..31
    const int t  = threadIdx.x;
    const int l  = t & 63;
    const int w  = t >> 6;
    const int wr = w >> 1, wc = w & 1;

    f32x4 acc[4][4];
    #pragma unroll
    for (int m = 0; m < 4; ++m)
        #pragma unroll
        for (int n = 0; n < 4; ++n)
            acc[m][n] = (f32x4)0.0f;

    const int srow = t >> 3;
    const int scol = (t & 7) * 8;
    const unsigned short* gA = Abf + ((size_t)(rt * 128 + srow) * ED) + scol;
    const unsigned short* gB = Bbf + ((size_t)(ct * 128 + srow) * ED) + scol;

    for (int k0 = 0; k0 < ED; k0 += 64) {
        #pragma unroll
        for (int j = 0; j < 4; ++j)
            __builtin_amdgcn_global_load_lds(
                (const __attribute__((address_space(1))) void*)(gA + (size_t)j * 32 * ED + k0),
                (__attribute__((address_space(3))) void*)(&As[j * 2048 + w * 512]),
                16, 0, 0);
        #pragma unroll
        for (int j = 0; j < 4; ++j)
            __builtin_amdgcn_global_load_lds(
                (const __attribute__((address_space(1))) void*)(gB + (size_t)j * 32 * ED + k0),
                (__attribute__((address_space(3))) void*)(&Bs[j * 2048 + w * 512]),
                16, 0, 0);
        __syncthreads();

        #pragma unroll
        for (int kk = 0; kk < 64; kk += 32) {
            bf16x8 af[4], bfr[4];
            #pragma unroll
            for (int m = 0; m < 4; ++m) {
                int r = wr * 64 + m * 16 + (l & 15);
                af[m] = *(const bf16x8*)&As[r * 64 + kk + (l >> 4) * 8];
            }
            #pragma unroll
            for (int n = 0; n < 4; ++n) {
                int r = wc * 64 + n * 16 + (l & 15);
                bfr[n] = *(const bf16x8*)&Bs[r * 64 + kk + (l >> 4) * 8];
            }
            #pragma unroll
            for (int m = 0; m < 4; ++m)
                #pragma unroll
                for (int n = 0; n < 4; ++n)
                    acc[m][n] = __builtin_amdgcn_mfma_f32_16x16x32_bf16(
                        af[m], bfr[n], acc[m][n], 0, 0, 0);
        }
        __syncthreads();
    }

    // epilogue: logits = acc * 20; per-row (over THIS WAVE's 64-col chunk)
    // max and sum-exp. C layout: col = l&15, row = (l>>4)*4 + reg. Row-mates
    // are the 16 lanes sharing (l>>4) -> xor masks 1,2,4,8.
    // Partial index: chunk = ct*2 + wc  (each wave owns its own chunk; no race
    // -- the Round-1 bug was both wc waves writing the same per-tile slot).
    const float SCALE = 20.0f;   // 1 / 0.05
    const int chunk = ct * 2 + wc;
    #pragma unroll
    for (int m = 0; m < 4; ++m) {
        #pragma unroll
        for (int j = 0; j < 4; ++j) {
            const int row_in = wr * 64 + m * 16 + (l >> 4) * 4 + j;
            float v0 = acc[m][0][j] * SCALE;
            float v1 = acc[m][1][j] * SCALE;
            float v2 = acc[m][2][j] * SCALE;
            float v3 = acc[m][3][j] * SCALE;
            if (ct == rt) {   // diagonal lives only in tiles ct==rt (pos half)
                const int R = rt * 128 + row_in;
                #pragma unroll
                for (int nn = 0; nn < 4; ++nn) {
                    int col_in = wc * 64 + nn * 16 + (l & 15);
                    float vv = (nn == 0) ? v0 : (nn == 1) ? v1 : (nn == 2) ? v2 : v3;
                    if (col_in == row_in) diag[R] = vv;
                }
            }
            float mx = fmaxf(fmaxf(v0, v1), fmaxf(v2, v3));
            #pragma unroll
            for (int off = 1; off < 16; off <<= 1)
                mx = fmaxf(mx, __shfl_xor(mx, off, 64));
            float s = expf(v0 - mx) + expf(v1 - mx) + expf(v2 - mx) + expf(v3 - mx);
            #pragma unroll
            for (int off = 1; off < 16; off <<= 1)
                s += __shfl_xor(s, off, 64);
            if ((l & 15) == 0) {
                const int R = rt * 128 + row_in;
                part_m[(size_t)chunk * NB + R] = mx;
                part_s[(size_t)chunk * NB + R] = s;
            }
        }
    }
}

// ---------- Kernel 3: merge 128 per-chunk partials per row, reduce loss ----------
__global__ __launch_bounds__(256) void combine(
    const float* __restrict__ part_m, const float* __restrict__ part_s,
    const float* __restrict__ diag, float* __restrict__ out)
{
    const int R = blockIdx.x * 256 + threadIdx.x;
    float M = -INFINITY;
    #pragma unroll 8
    for (int i = 0; i < CHUNKS; ++i)
        M = fmaxf(M, part_m[(size_t)i * NB + R]);
    float S = 0.0f;
    #pragma unroll 8
    for (int i = 0; i < CHUNKS; ++i)
        S += part_s[(size_t)i * NB + R] * expf(part_m[(size_t)i * NB + R] - M);
    float li = (M + logf(S)) - diag[R];   // lse - logit_ii

    #pragma unroll
    for (int off = 32; off > 0; off >>= 1) li += __shfl_down(li, off, 64);
    __shared__ float ws4[4];
    const int wv = threadIdx.x >> 6, ln = threadIdx.x & 63;
    if (ln == 0) ws4[wv] = li;
    __syncthreads();
    if (threadIdx.x == 0) {
        float tot = (ws4[0] + ws4[1] + ws4[2] + ws4[3]) * (1.0f / (float)NB);
        atomicAdd(out, tot);
    }
}

extern "C" void kernel_launch(void* const* d_in, const int* in_sizes, int n_in,
                              void* d_out, int out_size, void* d_ws, size_t ws_size,
                              hipStream_t stream) {
    const float* q = (const float*)d_in[0];
    const float* p = (const float*)d_in[1];
    const float* n = (const float*)d_in[2];
    char* wsb = (char*)d_ws;
    // ws layout: Abf 8MB | Bbf 16MB | part_m 2MB | part_s 2MB | diag 16KB (~28 MB)
    unsigned short* Abf = (unsigned short*)(wsb);
    unsigned short* Bbf = (unsigned short*)(wsb + ((size_t)8 << 20));
    float* part_m = (float*)(wsb + ((size_t)24 << 20));
    float* part_s = (float*)(wsb + ((size_t)26 << 20));
    float* diag   = (float*)(wsb + ((size_t)28 << 20));
    float* out = (float*)d_out;

    hipMemsetAsync(out, 0, sizeof(float), stream);
    normalize_cast<<<3 * NB, 256, 0, stream>>>(q, p, n, Abf, Bbf);
    gemm_softmax_partial<<<dim3(CT_TILES, RT_TILES), 256, 0, stream>>>(
        Abf, Bbf, part_m, part_s, diag);
    combine<<<NB / 256, 256, 0, stream>>>(part_m, part_s, diag, out);
}

// Round 3
// 180.038 us; speedup vs baseline: 1.3535x; 1.3535x over previous
//
#include <hip/hip_runtime.h>
#include <hip/hip_bf16.h>
#include <math.h>

#define NB 4096        // batch
#define ED 1024        // embed dim
#define NT 16          // K tiles: ED / 64
#define CHUNKS 128     // 8192 cols / 64 per-wave chunk
#define GEMM_GRID 512  // (4096/256) * (8192/256)

typedef __attribute__((ext_vector_type(8))) short bf16x8;
typedef __attribute__((ext_vector_type(4))) float f32x4;

__device__ inline unsigned short f2bf(float x) {
    unsigned u = __builtin_bit_cast(unsigned, x);
    unsigned r = (u + 0x7fffu + ((u >> 16) & 1u)) >> 16;
    return (unsigned short)r;
}

// ---------- Kernel 1: L2-normalize rows -> bf16. One wave per row, no block
// barriers (wave-level shfl reduce only). ----------
__global__ __launch_bounds__(256) void normalize_cast(
    const float* __restrict__ q, const float* __restrict__ p,
    const float* __restrict__ n,
    unsigned short* __restrict__ Abf, unsigned short* __restrict__ Bbf)
{
    const int w = threadIdx.x >> 6, l = threadIdx.x & 63;
    const int row = blockIdx.x * 4 + w;          // 0..12287
    const int mat = row >> 12;
    const int r = row & 4095;
    const float* src = (mat == 0) ? q : (mat == 1 ? p : n);
    src += (size_t)r * ED;
    unsigned short* dst = (mat == 0) ? (Abf + (size_t)r * ED)
                                     : (Bbf + ((size_t)(mat - 1) * NB + r) * ED);
    float4 v[4];
    #pragma unroll
    for (int i = 0; i < 4; ++i)
        v[i] = *(const float4*)(src + (size_t)(i * 64 + l) * 4);
    float ss = 0.f;
    #pragma unroll
    for (int i = 0; i < 4; ++i)
        ss += v[i].x * v[i].x + v[i].y * v[i].y + v[i].z * v[i].z + v[i].w * v[i].w;
    #pragma unroll
    for (int off = 1; off < 64; off <<= 1) ss += __shfl_xor(ss, off, 64);
    const float inv = 1.0f / fmaxf(sqrtf(ss), 1e-12f);
    #pragma unroll
    for (int i = 0; i < 4; ++i) {
        ushort4 o;
        o.x = f2bf(v[i].x * inv); o.y = f2bf(v[i].y * inv);
        o.z = f2bf(v[i].z * inv); o.w = f2bf(v[i].w * inv);
        *(ushort4*)(dst + (size_t)(i * 64 + l) * 4) = o;
    }
}

// ---------- Kernel 2: 256x256 tile, BK=64, 8 waves (2M x 4N), dbuf LDS with
// T2 XOR swizzle + counted vmcnt(8) pipeline + fused softmax partials ----------
__global__ __launch_bounds__(512, 2) void gemm_fused(
    const unsigned short* __restrict__ Abf, const unsigned short* __restrict__ Bbf,
    float* __restrict__ part_m, float* __restrict__ part_s,
    float* __restrict__ diag)
{
    extern __shared__ char smem[];   // A: [2][256][128B] at 0; B same at 65536

    // bijective XCD swizzle (512 % 8 == 0)
    const int orig = blockIdx.x;
    const int swz = (orig & 7) * (GEMM_GRID / 8) + (orig >> 3);
    const int rt = swz >> 5;    // 0..15  (M tile)
    const int ct = swz & 31;    // 0..31  (N tile)

    const int tid = threadIdx.x;
    const int w = tid >> 6, l = tid & 63;
    const int wm = w >> 2, wn = w & 3;

    // ---- staging addresses (pre-swizzled global source, linear LDS dest) ----
    const int srow = tid >> 3;                           // 0..63
    const int scol = ((tid & 7) ^ (srow & 7)) << 3;      // inverse-swizzled col (elems)
    const unsigned short* gA = Abf + (size_t)(rt * 256 + srow) * ED + scol;
    const unsigned short* gB = Bbf + (size_t)(ct * 256 + srow) * ED + scol;
    char* const ldsAw = smem + w * 1024;                 // + buf*32768 + j*8192
    char* const ldsBw = smem + 65536 + w * 1024;

#define STAGE(kt, b) do {                                                        \
    const unsigned short* _ga = gA + (kt) * 64;                                  \
    const unsigned short* _gb = gB + (kt) * 64;                                  \
    _Pragma("unroll")                                                            \
    for (int j = 0; j < 4; ++j)                                                  \
        __builtin_amdgcn_global_load_lds(                                        \
            (const __attribute__((address_space(1))) void*)(_ga + (size_t)j * 64 * ED), \
            (__attribute__((address_space(3))) void*)(ldsAw + (b) * 32768 + j * 8192),  \
            16, 0, 0);                                                           \
    _Pragma("unroll")                                                            \
    for (int j = 0; j < 4; ++j)                                                  \
        __builtin_amdgcn_global_load_lds(                                        \
            (const __attribute__((address_space(1))) void*)(_gb + (size_t)j * 64 * ED), \
            (__attribute__((address_space(3))) void*)(ldsBw + (b) * 32768 + j * 8192),  \
            16, 0, 0);                                                           \
} while (0)

    f32x4 acc[8][4];
    #pragma unroll
    for (int m = 0; m < 8; ++m)
        #pragma unroll
        for (int nn = 0; nn < 4; ++nn)
            acc[m][nn] = (f32x4)0.0f;

    // fragment-read lane constants
    const int frow = l & 15;
    const int fsel = (l >> 4) << 4;          // 0,16,32,48 (byte)
    const int xm = (l & 7) << 4;             // XOR swizzle mask (byte)

    // ---- prologue: stage tiles 0,1; wait tile 0 ----
    STAGE(0, 0);
    STAGE(1, 1);
    asm volatile("s_waitcnt vmcnt(8)" ::: "memory");
    __builtin_amdgcn_s_barrier();
    __builtin_amdgcn_sched_barrier(0);

    for (int t = 0; t < NT; ++t) {
        const int b = t & 1;
        const char* Ab = smem + b * 32768;
        const char* Bb = smem + 65536 + b * 32768;
        #pragma unroll
        for (int s = 0; s < 2; ++s) {
            const int cbyte = (s * 64 + fsel) ^ xm;
            bf16x8 a[8], bb[4];
            #pragma unroll
            for (int m = 0; m < 8; ++m)
                a[m] = *(const bf16x8*)(Ab + (wm * 128 + m * 16 + frow) * 128 + cbyte);
            #pragma unroll
            for (int nn = 0; nn < 4; ++nn)
                bb[nn] = *(const bf16x8*)(Bb + (wn * 64 + nn * 16 + frow) * 128 + cbyte);
            __builtin_amdgcn_s_setprio(1);
            #pragma unroll
            for (int m = 0; m < 8; ++m)
                #pragma unroll
                for (int nn = 0; nn < 4; ++nn)
                    acc[m][nn] = __builtin_amdgcn_mfma_f32_16x16x32_bf16(
                        a[m], bb[nn], acc[m][nn], 0, 0, 0);
            __builtin_amdgcn_s_setprio(0);
        }
        if (t == NT - 1) break;
        // release cur buffer (all waves' ds_reads retired)
        asm volatile("s_waitcnt lgkmcnt(0)" ::: "memory");
        __builtin_amdgcn_sched_barrier(0);
        __builtin_amdgcn_s_barrier();
        __builtin_amdgcn_sched_barrier(0);
        if (t + 2 < NT) {
            STAGE(t + 2, b);
            asm volatile("s_waitcnt vmcnt(8)" ::: "memory");   // tile t+1 landed
        } else {
            asm volatile("s_waitcnt vmcnt(0)" ::: "memory");   // tail drain
        }
        __builtin_amdgcn_sched_barrier(0);
        __builtin_amdgcn_s_barrier();
        __builtin_amdgcn_sched_barrier(0);
    }
#undef STAGE

    // ---- epilogue: x20 scale, per-wave 64-col chunk (max, sum-exp), diag ----
    const float SCALE = 20.0f;   // 1 / 0.05
    const int chunk = ct * 4 + wn;
    const int rbase = rt * 256 + wm * 128;
    const int g = l >> 4;
    #pragma unroll
    for (int m = 0; m < 8; ++m) {
        #pragma unroll
        for (int j = 0; j < 4; ++j) {
            float v0 = acc[m][0][j] * SCALE;
            float v1 = acc[m][1][j] * SCALE;
            float v2 = acc[m][2][j] * SCALE;
            float v3 = acc[m][3][j] * SCALE;
            const int row_in_block = wm * 128 + m * 16 + g * 4 + j;
            if (ct == rt) {   // diagonal (labels[i]=i, pos half cols)
                #pragma unroll
                for (int nn = 0; nn < 4; ++nn) {
                    const int col_in_block = wn * 64 + nn * 16 + (l & 15);
                    float vv = (nn == 0) ? v0 : (nn == 1) ? v1 : (nn == 2) ? v2 : v3;
                    if (col_in_block == row_in_block)
                        diag[rt * 256 + row_in_block] = vv;
                }
            }
            float mx = fmaxf(fmaxf(v0, v1), fmaxf(v2, v3));
            #pragma unroll
            for (int off = 1; off < 16; off <<= 1)
                mx = fmaxf(mx, __shfl_xor(mx, off, 64));
            float sum = __expf(v0 - mx) + __expf(v1 - mx)
                      + __expf(v2 - mx) + __expf(v3 - mx);
            #pragma unroll
            for (int off = 1; off < 16; off <<= 1)
                sum += __shfl_xor(sum, off, 64);
            if ((l & 15) == 0) {
                const int R = rbase + m * 16 + g * 4 + j;
                part_m[(size_t)chunk * NB + R] = mx;
                part_s[(size_t)chunk * NB + R] = sum;
            }
        }
    }
}

// ---------- Kernel 3: merge 128 per-chunk partials per row, reduce loss ----------
// 64 blocks x 256 thr; block handles 64 rows; 4 strips of 32 chunks.
__global__ __launch_bounds__(256) void combine(
    const float* __restrict__ part_m, const float* __restrict__ part_s,
    const float* __restrict__ diag, float* __restrict__ out)
{
    const int l = threadIdx.x & 63;
    const int strip = threadIdx.x >> 6;
    const int R = blockIdx.x * 64 + l;

    float M = -INFINITY;
    #pragma unroll 8
    for (int i = strip * 32; i < strip * 32 + 32; ++i)
        M = fmaxf(M, part_m[(size_t)i * NB + R]);
    float S = 0.0f;
    #pragma unroll 8
    for (int i = strip * 32; i < strip * 32 + 32; ++i)
        S += part_s[(size_t)i * NB + R] * __expf(part_m[(size_t)i * NB + R] - M);

    __shared__ float sm[4][64], ssum[4][64];
    sm[strip][l] = M; ssum[strip][l] = S;
    __syncthreads();
    if (strip == 0) {
        float Mf = fmaxf(fmaxf(sm[0][l], sm[1][l]), fmaxf(sm[2][l], sm[3][l]));
        float Sf = 0.0f;
        #pragma unroll
        for (int k = 0; k < 4; ++k)
            Sf += ssum[k][l] * __expf(sm[k][l] - Mf);
        float li = (Mf + logf(Sf)) - diag[R];
        #pragma unroll
        for (int off = 1; off < 64; off <<= 1) li += __shfl_xor(li, off, 64);
        if (l == 0) atomicAdd(out, li * (1.0f / (float)NB));
    }
}

extern "C" void kernel_launch(void* const* d_in, const int* in_sizes, int n_in,
                              void* d_out, int out_size, void* d_ws, size_t ws_size,
                              hipStream_t stream) {
    const float* q = (const float*)d_in[0];
    const float* p = (const float*)d_in[1];
    const float* n = (const float*)d_in[2];
    char* wsb = (char*)d_ws;
    // ws: Abf 8MB | Bbf 16MB | part_m 2MB | part_s 2MB | diag 16KB
    unsigned short* Abf = (unsigned short*)(wsb);
    unsigned short* Bbf = (unsigned short*)(wsb + ((size_t)8 << 20));
    float* part_m = (float*)(wsb + ((size_t)24 << 20));
    float* part_s = (float*)(wsb + ((size_t)26 << 20));
    float* diag   = (float*)(wsb + ((size_t)28 << 20));
    float* out = (float*)d_out;

    (void)hipFuncSetAttribute(reinterpret_cast<const void*>(&gemm_fused),
                              hipFuncAttributeMaxDynamicSharedMemorySize, 131072);

    hipMemsetAsync(out, 0, sizeof(float), stream);
    normalize_cast<<<3 * NB / 4, 256, 0, stream>>>(q, p, n, Abf, Bbf);
    gemm_fused<<<GEMM_GRID, 512, 131072, stream>>>(Abf, Bbf, part_m, part_s, diag);
    combine<<<NB / 64, 256, 0, stream>>>(part_m, part_s, diag, out);
}

// Round 5
// 178.263 us; speedup vs baseline: 1.3669x; 1.0100x over previous
//
#include <hip/hip_runtime.h>
#include <hip/hip_bf16.h>
#include <math.h>

#define NB 4096        // batch
#define ED 1024        // embed dim
#define NT 16          // K tiles: ED / 64
#define CHUNKS 128     // 8192 cols / 64 per-wave chunk
#define GEMM_GRID 512  // (4096/256) * (8192/256)

typedef __attribute__((ext_vector_type(8))) short bf16x8;
typedef __attribute__((ext_vector_type(4))) float f32x4;

__device__ inline unsigned short f2bf(float x) {
    unsigned u = __builtin_bit_cast(unsigned, x);
    unsigned r = (u + 0x7fffu + ((u >> 16) & 1u)) >> 16;
    return (unsigned short)r;
}

// ---------- Kernel 1: L2-normalize rows -> bf16. One wave per row. ----------
__global__ __launch_bounds__(256) void normalize_cast(
    const float* __restrict__ q, const float* __restrict__ p,
    const float* __restrict__ n,
    unsigned short* __restrict__ Abf, unsigned short* __restrict__ Bbf)
{
    const int w = threadIdx.x >> 6, l = threadIdx.x & 63;
    const int row = blockIdx.x * 4 + w;          // 0..12287
    const int mat = row >> 12;
    const int r = row & 4095;
    const float* src = (mat == 0) ? q : (mat == 1 ? p : n);
    src += (size_t)r * ED;
    unsigned short* dst = (mat == 0) ? (Abf + (size_t)r * ED)
                                     : (Bbf + ((size_t)(mat - 1) * NB + r) * ED);
    float4 v[4];
    #pragma unroll
    for (int i = 0; i < 4; ++i)
        v[i] = *(const float4*)(src + (size_t)(i * 64 + l) * 4);
    float ss = 0.f;
    #pragma unroll
    for (int i = 0; i < 4; ++i)
        ss += v[i].x * v[i].x + v[i].y * v[i].y + v[i].z * v[i].z + v[i].w * v[i].w;
    #pragma unroll
    for (int off = 1; off < 64; off <<= 1) ss += __shfl_xor(ss, off, 64);
    const float inv = 1.0f / fmaxf(sqrtf(ss), 1e-12f);
    #pragma unroll
    for (int i = 0; i < 4; ++i) {
        ushort4 o;
        o.x = f2bf(v[i].x * inv); o.y = f2bf(v[i].y * inv);
        o.z = f2bf(v[i].z * inv); o.w = f2bf(v[i].w * inv);
        *(ushort4*)(dst + (size_t)(i * 64 + l) * 4) = o;
    }
}

// ---------- Kernel 2: 256x256 tile, BK=64, 8 waves (2M x 4N), dbuf LDS with
// T2 XOR swizzle + counted vmcnt(8) pipeline + fused softmax partials.
// R4 change: 2D XCD-rectangle block swizzle (8rt x 8ct per XCD, serpentine)
// to cut per-XCD L2 working set from {2 A-panels + ALL of B} (17 MB) to
// {8 A + 8 B panels} (8 MB) -> FETCH_SIZE 135 MB -> ~60-90 MB. ----------
__global__ __launch_bounds__(512, 2) void gemm_fused(
    const unsigned short* __restrict__ Abf, const unsigned short* __restrict__ Bbf,
    float* __restrict__ part_m, float* __restrict__ part_s,
    float* __restrict__ diag)
{
    extern __shared__ char smem[];   // A: [2][256 rows][128B] at 0; B at 65536

    // ---- 2D XCD-rectangle swizzle (bid%8 == XCD round-robin heuristic) ----
    // 16 rt x 32 ct grid of tiles; XCD x owns rectangle:
    //   rt in [ (x&1)*8, +8 ),  ct in [ (x>>1)*8, +8 )   (64 blocks each)
    // serpentine in ct so consecutive co-resident blocks share A/B panels.
    const int bid = blockIdx.x;
    const int xcd = bid & 7;
    const int idx = bid >> 3;             // 0..63 within rectangle
    const int lr  = idx >> 3;             // 0..7
    const int lcr = idx & 7;
    const int lc  = (lr & 1) ? (7 - lcr) : lcr;
    const int rt  = (xcd & 1) * 8 + lr;   // 0..15
    const int ct  = (xcd >> 1) * 8 + lc;  // 0..31

    const int tid = threadIdx.x;
    const int w = tid >> 6, l = tid & 63;
    const int wm = w >> 2, wn = w & 3;

    // ---- staging addresses (pre-swizzled global source, linear LDS dest) ----
    const int srow = tid >> 3;                           // 0..63
    const int scol = ((tid & 7) ^ (srow & 7)) << 3;      // inverse-swizzled col
    const unsigned short* gA = Abf + (size_t)(rt * 256 + srow) * ED + scol;
    const unsigned short* gB = Bbf + (size_t)(ct * 256 + srow) * ED + scol;
    char* const ldsAw = smem + w * 1024;                 // + buf*32768 + j*8192
    char* const ldsBw = smem + 65536 + w * 1024;

#define STAGE(kt, b) do {                                                        \
    const unsigned short* _ga = gA + (kt) * 64;                                  \
    const unsigned short* _gb = gB + (kt) * 64;                                  \
    _Pragma("unroll")                                                            \
    for (int j = 0; j < 4; ++j)                                                  \
        __builtin_amdgcn_global_load_lds(                                        \
            (const __attribute__((address_space(1))) void*)(_ga + (size_t)j * 64 * ED), \
            (__attribute__((address_space(3))) void*)(ldsAw + (b) * 32768 + j * 8192),  \
            16, 0, 0);                                                           \
    _Pragma("unroll")                                                            \
    for (int j = 0; j < 4; ++j)                                                  \
        __builtin_amdgcn_global_load_lds(                                        \
            (const __attribute__((address_space(1))) void*)(_gb + (size_t)j * 64 * ED), \
            (__attribute__((address_space(3))) void*)(ldsBw + (b) * 32768 + j * 8192),  \
            16, 0, 0);                                                           \
} while (0)

    f32x4 acc[8][4];
    #pragma unroll
    for (int m = 0; m < 8; ++m)
        #pragma unroll
        for (int nn = 0; nn < 4; ++nn)
            acc[m][nn] = (f32x4)0.0f;

    const int frow = l & 15;
    const int fsel = (l >> 4) << 4;          // 0,16,32,48 (byte)
    const int xm = (l & 7) << 4;             // XOR swizzle mask (byte)

    // ---- prologue: stage tiles 0,1; wait tile 0 ----
    STAGE(0, 0);
    STAGE(1, 1);
    asm volatile("s_waitcnt vmcnt(8)" ::: "memory");
    __builtin_amdgcn_s_barrier();
    __builtin_amdgcn_sched_barrier(0);

    for (int t = 0; t < NT; ++t) {
        const int b = t & 1;
        const char* Ab = smem + b * 32768;
        const char* Bb = smem + 65536 + b * 32768;
        #pragma unroll
        for (int s = 0; s < 2; ++s) {
            const int cbyte = (s * 64 + fsel) ^ xm;
            bf16x8 a[8], bb[4];
            #pragma unroll
            for (int m = 0; m < 8; ++m)
                a[m] = *(const bf16x8*)(Ab + (wm * 128 + m * 16 + frow) * 128 + cbyte);
            #pragma unroll
            for (int nn = 0; nn < 4; ++nn)
                bb[nn] = *(const bf16x8*)(Bb + (wn * 64 + nn * 16 + frow) * 128 + cbyte);
            __builtin_amdgcn_s_setprio(1);
            #pragma unroll
            for (int m = 0; m < 8; ++m)
                #pragma unroll
                for (int nn = 0; nn < 4; ++nn)
                    acc[m][nn] = __builtin_amdgcn_mfma_f32_16x16x32_bf16(
                        a[m], bb[nn], acc[m][nn], 0, 0, 0);
            __builtin_amdgcn_s_setprio(0);
        }
        if (t == NT - 1) break;
        // release cur buffer (all waves' ds_reads retired)
        asm volatile("s_waitcnt lgkmcnt(0)" ::: "memory");
        __builtin_amdgcn_sched_barrier(0);
        __builtin_amdgcn_s_barrier();
        __builtin_amdgcn_sched_barrier(0);
        if (t + 2 < NT) {
            STAGE(t + 2, b);
            asm volatile("s_waitcnt vmcnt(8)" ::: "memory");   // tile t+1 landed
        } else {
            asm volatile("s_waitcnt vmcnt(0)" ::: "memory");   // tail drain
        }
        __builtin_amdgcn_sched_barrier(0);
        __builtin_amdgcn_s_barrier();
        __builtin_amdgcn_sched_barrier(0);
    }
#undef STAGE

    // ---- epilogue: x20 scale, per-wave 64-col chunk (max, sum-exp), diag ----
    const float SCALE = 20.0f;   // 1 / 0.05
    const int chunk = ct * 4 + wn;
    const int rbase = rt * 256 + wm * 128;
    const int g = l >> 4;
    #pragma unroll
    for (int m = 0; m < 8; ++m) {
        #pragma unroll
        for (int j = 0; j < 4; ++j) {
            float v0 = acc[m][0][j] * SCALE;
            float v1 = acc[m][1][j] * SCALE;
            float v2 = acc[m][2][j] * SCALE;
            float v3 = acc[m][3][j] * SCALE;
            const int row_in_block = wm * 128 + m * 16 + g * 4 + j;
            if (ct == rt) {   // diagonal (labels[i]=i, pos half cols)
                #pragma unroll
                for (int nn = 0; nn < 4; ++nn) {
                    const int col_in_block = wn * 64 + nn * 16 + (l & 15);
                    float vv = (nn == 0) ? v0 : (nn == 1) ? v1 : (nn == 2) ? v2 : v3;
                    if (col_in_block == row_in_block)
                        diag[rt * 256 + row_in_block] = vv;
                }
            }
            float mx = fmaxf(fmaxf(v0, v1), fmaxf(v2, v3));
            #pragma unroll
            for (int off = 1; off < 16; off <<= 1)
                mx = fmaxf(mx, __shfl_xor(mx, off, 64));
            float sum = __expf(v0 - mx) + __expf(v1 - mx)
                      + __expf(v2 - mx) + __expf(v3 - mx);
            #pragma unroll
            for (int off = 1; off < 16; off <<= 1)
                sum += __shfl_xor(sum, off, 64);
            if ((l & 15) == 0) {
                const int R = rbase + m * 16 + g * 4 + j;
                part_m[(size_t)chunk * NB + R] = mx;
                part_s[(size_t)chunk * NB + R] = sum;
            }
        }
    }
}

// ---------- Kernel 3: merge 128 per-chunk partials per row, reduce loss ----------
__global__ __launch_bounds__(256) void combine(
    const float* __restrict__ part_m, const float* __restrict__ part_s,
    const float* __restrict__ diag, float* __restrict__ out)
{
    const int l = threadIdx.x & 63;
    const int strip = threadIdx.x >> 6;
    const int R = blockIdx.x * 64 + l;

    float M = -INFINITY;
    #pragma unroll 8
    for (int i = strip * 32; i < strip * 32 + 32; ++i)
        M = fmaxf(M, part_m[(size_t)i * NB + R]);
    float S = 0.0f;
    #pragma unroll 8
    for (int i = strip * 32; i < strip * 32 + 32; ++i)
        S += part_s[(size_t)i * NB + R] * __expf(part_m[(size_t)i * NB + R] - M);

    __shared__ float sm[4][64], ssum[4][64];
    sm[strip][l] = M; ssum[strip][l] = S;
    __syncthreads();
    if (strip == 0) {
        float Mf = fmaxf(fmaxf(sm[0][l], sm[1][l]), fmaxf(sm[2][l], sm[3][l]));
        float Sf = 0.0f;
        #pragma unroll
        for (int k = 0; k < 4; ++k)
            Sf += ssum[k][l] * __expf(sm[k][l] - Mf);
        float li = (Mf + logf(Sf)) - diag[R];
        #pragma unroll
        for (int off = 1; off < 64; off <<= 1) li += __shfl_xor(li, off, 64);
        if (l == 0) atomicAdd(out, li * (1.0f / (float)NB));
    }
}

extern "C" void kernel_launch(void* const* d_in, const int* in_sizes, int n_in,
                              void* d_out, int out_size, void* d_ws, size_t ws_size,
                              hipStream_t stream) {
    const float* q = (const float*)d_in[0];
    const float* p = (const float*)d_in[1];
    const float* n = (const float*)d_in[2];
    char* wsb = (char*)d_ws;
    // ws: Abf 8MB | Bbf 16MB | part_m 2MB | part_s 2MB | diag 16KB
    unsigned short* Abf = (unsigned short*)(wsb);
    unsigned short* Bbf = (unsigned short*)(wsb + ((size_t)8 << 20));
    float* part_m = (float*)(wsb + ((size_t)24 << 20));
    float* part_s = (float*)(wsb + ((size_t)26 << 20));
    float* diag   = (float*)(wsb + ((size_t)28 << 20));
    float* out = (float*)d_out;

    (void)hipFuncSetAttribute(reinterpret_cast<const void*>(&gemm_fused),
                              hipFuncAttributeMaxDynamicSharedMemorySize, 131072);

    hipMemsetAsync(out, 0, sizeof(float), stream);
    normalize_cast<<<3 * NB / 4, 256, 0, stream>>>(q, p, n, Abf, Bbf);
    gemm_fused<<<GEMM_GRID, 512, 131072, stream>>>(Abf, Bbf, part_m, part_s, diag);
    combine<<<NB / 64, 256, 0, stream>>>(part_m, part_s, diag, out);
}

// Round 8
// 171.034 us; speedup vs baseline: 1.4247x; 1.0423x over previous
//
#include <hip/hip_runtime.h>
#include <hip/hip_bf16.h>
#include <math.h>

#define NB 4096        // batch
#define ED 1024        // embed dim
#define NT 16          // K tiles: ED / 64
#define CHUNKS 128     // 8192 cols / 64-col (virtual) per-wave chunk
#define GEMM_GRID 512  // (4096/256) * (8192/256)

typedef __attribute__((ext_vector_type(8))) short bf16x8;
typedef __attribute__((ext_vector_type(4))) float f32x4;

#define AS1 __attribute__((address_space(1)))
#define AS3 __attribute__((address_space(3)))

__device__ inline unsigned short f2bf(float x) {
    unsigned u = __builtin_bit_cast(unsigned, x);
    unsigned r = (u + 0x7fffu + ((u >> 16) & 1u)) >> 16;
    return (unsigned short)r;
}

// ---------- Kernel 1: L2-normalize rows -> bf16. One wave per row. ----------
__global__ __launch_bounds__(256) void normalize_cast(
    const float* __restrict__ q, const float* __restrict__ p,
    const float* __restrict__ n,
    unsigned short* __restrict__ Abf, unsigned short* __restrict__ Bbf)
{
    const int w = threadIdx.x >> 6, l = threadIdx.x & 63;
    const int row = blockIdx.x * 4 + w;          // 0..12287
    const int mat = row >> 12;
    const int r = row & 4095;
    const float* src = (mat == 0) ? q : (mat == 1 ? p : n);
    src += (size_t)r * ED;
    unsigned short* dst = (mat == 0) ? (Abf + (size_t)r * ED)
                                     : (Bbf + ((size_t)(mat - 1) * NB + r) * ED);
    float4 v[4];
    #pragma unroll
    for (int i = 0; i < 4; ++i)
        v[i] = *(const float4*)(src + (size_t)(i * 64 + l) * 4);
    float ss = 0.f;
    #pragma unroll
    for (int i = 0; i < 4; ++i)
        ss += v[i].x * v[i].x + v[i].y * v[i].y + v[i].z * v[i].z + v[i].w * v[i].w;
    #pragma unroll
    for (int off = 1; off < 64; off <<= 1) ss += __shfl_xor(ss, off, 64);
    const float inv = 1.0f / fmaxf(sqrtf(ss), 1e-12f);
    #pragma unroll
    for (int i = 0; i < 4; ++i) {
        ushort4 o;
        o.x = f2bf(v[i].x * inv); o.y = f2bf(v[i].y * inv);
        o.z = f2bf(v[i].z * inv); o.w = f2bf(v[i].w * inv);
        *(ushort4*)(dst + (size_t)(i * 64 + l) * 4) = o;
    }
}

// ---------- Kernel 2: 256x256 tile, BK=64, 8 waves, INTERLEAVED wave tiling
// (wave wm owns row-blocks j*32+wm*16; wave wn owns col-blocks i*64+wn*16),
// 4 phases/K-tile (16 MFMA each), 2 staging ops/phase, counted vmcnt(4) at
// each K-tile boundary (never 0 until tail). T1 2D-XCD rect + T2 swizzle
// + T5 setprio, all carried from R5. ----------
__global__ __launch_bounds__(512, 2) void gemm_fused(
    const unsigned short* __restrict__ Abf, const unsigned short* __restrict__ Bbf,
    float* __restrict__ part_m, float* __restrict__ part_s,
    float* __restrict__ diag)
{
    extern __shared__ char smem[];   // A: [2][256 rows][128B] at 0; B at 65536

    // ---- 2D XCD-rectangle swizzle (proven R5: FETCH 135->49 MB) ----
    const int bid = blockIdx.x;
    const int xcd = bid & 7;
    const int idx = bid >> 3;             // 0..63 within rectangle
    const int lr  = idx >> 3;             // 0..7
    const int lcr = idx & 7;
    const int lc  = (lr & 1) ? (7 - lcr) : lcr;
    const int rt  = (xcd & 1) * 8 + lr;   // 0..15
    const int ct  = (xcd >> 1) * 8 + lc;  // 0..31

    const int tid = threadIdx.x;
    const int w = tid >> 6, l = tid & 63;
    const int wm = w >> 2, wn = w & 3;

    // ---- staging addresses (pre-swizzled global source, linear LDS dest) ----
    const int srow = tid >> 3;                           // 0..63
    const int scol = ((tid & 7) ^ (srow & 7)) << 3;      // inverse-swizzled col
    const unsigned short* gA = Abf + (size_t)(rt * 256 + srow) * ED + scol;
    const unsigned short* gB = Bbf + (size_t)(ct * 256 + srow) * ED + scol;

// 2 staging ops (= one 64-row half-of-half) for A / B: ops o0, o0+1
#define STG_A2(kt, buf, o0) do {                                                   \
    __builtin_amdgcn_global_load_lds(                                              \
        (const AS1 void*)(gA + (size_t)(o0) * 64 * ED + (kt) * 64),                \
        (AS3 void*)(smem + (buf) * 32768 + (o0) * 8192 + w * 1024), 16, 0, 0);     \
    __builtin_amdgcn_global_load_lds(                                              \
        (const AS1 void*)(gA + (size_t)((o0) + 1) * 64 * ED + (kt) * 64),          \
        (AS3 void*)(smem + (buf) * 32768 + ((o0) + 1) * 8192 + w * 1024), 16, 0, 0);\
} while (0)
#define STG_B2(kt, buf, o0) do {                                                   \
    __builtin_amdgcn_global_load_lds(                                              \
        (const AS1 void*)(gB + (size_t)(o0) * 64 * ED + (kt) * 64),                \
        (AS3 void*)(smem + 65536 + (buf) * 32768 + (o0) * 8192 + w * 1024), 16, 0, 0);\
    __builtin_amdgcn_global_load_lds(                                              \
        (const AS1 void*)(gB + (size_t)((o0) + 1) * 64 * ED + (kt) * 64),          \
        (AS3 void*)(smem + 65536 + (buf) * 32768 + ((o0) + 1) * 8192 + w * 1024), 16, 0, 0);\
} while (0)

    f32x4 acc[8][4];
    #pragma unroll
    for (int j = 0; j < 8; ++j)
        #pragma unroll
        for (int i = 0; i < 4; ++i)
            acc[j][i] = (f32x4)0.0f;

    const int frow  = l & 15;
    const int fsel  = (l >> 4) << 4;         // 0,16,32,48 (byte)
    const int xm    = (l & 7) << 4;          // XOR swizzle mask (byte)
    const int wm16f = wm * 16 + frow;        // A row base within 32-row block
    const int wn16f = wn * 16 + frow;        // B row base within 64-row block

// fragment reads (swizzled; row = j*32+wm*16+frow ≡ frow mod 8 -> xm valid)
#define LDA(Ab, j, kk) (*(const bf16x8*)((Ab) + ((j) * 32 + wm16f) * 128 + (((kk) * 64 + fsel) ^ xm)))
#define LDB(Bb, i, kk) (*(const bf16x8*)((Bb) + ((i) * 64 + wn16f) * 128 + (((kk) * 64 + fsel) ^ xm)))

#define MIDBAR()  do { __builtin_amdgcn_s_barrier();                               \
    asm volatile("s_waitcnt lgkmcnt(0)" ::: "memory");                             \
    __builtin_amdgcn_sched_barrier(0); } while (0)
#define ENDBAR()  do { __builtin_amdgcn_s_barrier();                               \
    __builtin_amdgcn_sched_barrier(0); } while (0)

    // ---- prologue: tile0 full + tile1's {A-h0, B-h1}; wait tile0 ----
    STG_A2(0, 0, 0); STG_A2(0, 0, 2); STG_B2(0, 0, 0); STG_B2(0, 0, 2);
    STG_A2(1, 1, 0); STG_B2(1, 1, 2);
    asm volatile("s_waitcnt vmcnt(4)" ::: "memory");
    __builtin_amdgcn_s_barrier();
    __builtin_amdgcn_sched_barrier(0);

    for (int t = 0; t < NT; ++t) {
        const int b = t & 1;
        const char* Ab = smem + b * 32768;
        const char* Bb = smem + 65536 + b * 32768;
        bf16x8 a[4][2], bb[2][2];

        // ---- P0: quadrant (mh=0, nh=0): reads A j0-3 + B i0-1 (12) ----
        #pragma unroll
        for (int j = 0; j < 4; ++j) { a[j][0] = LDA(Ab, j, 0); a[j][1] = LDA(Ab, j, 1); }
        #pragma unroll
        for (int i = 0; i < 2; ++i) { bb[i][0] = LDB(Bb, i, 0); bb[i][1] = LDB(Bb, i, 1); }
        if (t + 1 < NT) STG_A2(t + 1, b ^ 1, 2);   // A-h1(t+1); dead since P2 of t-1
        MIDBAR();
        __builtin_amdgcn_s_setprio(1);
        #pragma unroll
        for (int j = 0; j < 4; ++j)
            #pragma unroll
            for (int i = 0; i < 2; ++i) {
                acc[j][i] = __builtin_amdgcn_mfma_f32_16x16x32_bf16(a[j][0], bb[i][0], acc[j][i], 0, 0, 0);
                acc[j][i] = __builtin_amdgcn_mfma_f32_16x16x32_bf16(a[j][1], bb[i][1], acc[j][i], 0, 0, 0);
            }
        __builtin_amdgcn_s_setprio(0);
        ENDBAR();

        // ---- P1: (0,1): reads B i2-3 (4); A held ----
        #pragma unroll
        for (int i = 0; i < 2; ++i) { bb[i][0] = LDB(Bb, i + 2, 0); bb[i][1] = LDB(Bb, i + 2, 1); }
        if (t + 1 < NT) STG_B2(t + 1, b ^ 1, 0);   // B-h0(t+1); dead since P3 of t-1
        MIDBAR();
        __builtin_amdgcn_s_setprio(1);
        #pragma unroll
        for (int j = 0; j < 4; ++j)
            #pragma unroll
            for (int i = 0; i < 2; ++i) {
                acc[j][2 + i] = __builtin_amdgcn_mfma_f32_16x16x32_bf16(a[j][0], bb[i][0], acc[j][2 + i], 0, 0, 0);
                acc[j][2 + i] = __builtin_amdgcn_mfma_f32_16x16x32_bf16(a[j][1], bb[i][1], acc[j][2 + i], 0, 0, 0);
            }
        __builtin_amdgcn_s_setprio(0);
        ENDBAR();

        // ---- P2: (1,1): reads A j4-7 (8); B held ----
        #pragma unroll
        for (int j = 0; j < 4; ++j) { a[j][0] = LDA(Ab, j + 4, 0); a[j][1] = LDA(Ab, j + 4, 1); }
        if (t + 2 < NT) STG_A2(t + 2, b, 0);       // A-h0(t+2); t's A-h0 dead since P0
        MIDBAR();
        __builtin_amdgcn_s_setprio(1);
        #pragma unroll
        for (int j = 0; j < 4; ++j)
            #pragma unroll
            for (int i = 0; i < 2; ++i) {
                acc[4 + j][2 + i] = __builtin_amdgcn_mfma_f32_16x16x32_bf16(a[j][0], bb[i][0], acc[4 + j][2 + i], 0, 0, 0);
                acc[4 + j][2 + i] = __builtin_amdgcn_mfma_f32_16x16x32_bf16(a[j][1], bb[i][1], acc[4 + j][2 + i], 0, 0, 0);
            }
        __builtin_amdgcn_s_setprio(0);
        ENDBAR();

        // ---- P3: (1,0): re-reads B i0-1 (4) ----
        #pragma unroll
        for (int i = 0; i < 2; ++i) { bb[i][0] = LDB(Bb, i, 0); bb[i][1] = LDB(Bb, i, 1); }
        if (t + 2 < NT) STG_B2(t + 2, b, 2);       // B-h1(t+2); t's B-h1 dead since P1
        MIDBAR();
        __builtin_amdgcn_s_setprio(1);
        #pragma unroll
        for (int j = 0; j < 4; ++j)
            #pragma unroll
            for (int i = 0; i < 2; ++i) {
                acc[4 + j][i] = __builtin_amdgcn_mfma_f32_16x16x32_bf16(a[j][0], bb[i][0], acc[4 + j][i], 0, 0, 0);
                acc[4 + j][i] = __builtin_amdgcn_mfma_f32_16x16x32_bf16(a[j][1], bb[i][1], acc[4 + j][i], 0, 0, 0);
            }
        __builtin_amdgcn_s_setprio(0);
        // K-tile boundary: counted wait (tile t+1 fully landed; 4 newest =
        // this tile's P2/P3 staging for t+2 may stay in flight).
        if (t + 2 < NT)      { asm volatile("s_waitcnt vmcnt(4)" ::: "memory"); }
        else if (t + 1 < NT) { asm volatile("s_waitcnt vmcnt(0)" ::: "memory"); }
        ENDBAR();
    }
#undef STG_A2
#undef STG_B2
#undef LDA
#undef LDB

    // ---- epilogue: x20, per-wave virtual 64-col chunk (cols ≡ wn*16 mod 64
    // within ct block), shfl over 16 row-mates, diag extraction ----
    const float SCALE = 20.0f;   // 1 / 0.05
    const int chunk = ct * 4 + wn;
    const int g = l >> 4;
    #pragma unroll
    for (int j = 0; j < 8; ++j) {
        #pragma unroll
        for (int jj = 0; jj < 4; ++jj) {
            const int row_in_block = j * 32 + wm * 16 + g * 4 + jj;
            float v0 = acc[j][0][jj] * SCALE;
            float v1 = acc[j][1][jj] * SCALE;
            float v2 = acc[j][2][jj] * SCALE;
            float v3 = acc[j][3][jj] * SCALE;
            if (ct == rt) {   // diagonal (labels[i]=i, pos half cols)
                #pragma unroll
                for (int i = 0; i < 4; ++i) {
                    const int col_in_block = i * 64 + wn * 16 + (l & 15);
                    float vv = (i == 0) ? v0 : (i == 1) ? v1 : (i == 2) ? v2 : v3;
                    if (col_in_block == row_in_block)
                        diag[rt * 256 + row_in_block] = vv;
                }
            }
            float mx = fmaxf(fmaxf(v0, v1), fmaxf(v2, v3));
            #pragma unroll
            for (int off = 1; off < 16; off <<= 1)
                mx = fmaxf(mx, __shfl_xor(mx, off, 64));
            float sum = __expf(v0 - mx) + __expf(v1 - mx)
                      + __expf(v2 - mx) + __expf(v3 - mx);
            #pragma unroll
            for (int off = 1; off < 16; off <<= 1)
                sum += __shfl_xor(sum, off, 64);
            if ((l & 15) == 0) {
                const int R = rt * 256 + row_in_block;
                part_m[(size_t)chunk * NB + R] = mx;
                part_s[(size_t)chunk * NB + R] = sum;
            }
        }
    }
}

// ---------- Kernel 3: merge 128 per-chunk partials per row, reduce loss ----------
__global__ __launch_bounds__(256) void combine(
    const float* __restrict__ part_m, const float* __restrict__ part_s,
    const float* __restrict__ diag, float* __restrict__ out)
{
    const int l = threadIdx.x & 63;
    const int strip = threadIdx.x >> 6;
    const int R = blockIdx.x * 64 + l;

    float M = -INFINITY;
    #pragma unroll 8
    for (int i = strip * 32; i < strip * 32 + 32; ++i)
        M = fmaxf(M, part_m[(size_t)i * NB + R]);
    float S = 0.0f;
    #pragma unroll 8
    for (int i = strip * 32; i < strip * 32 + 32; ++i)
        S += part_s[(size_t)i * NB + R] * __expf(part_m[(size_t)i * NB + R] - M);

    __shared__ float sm[4][64], ssum[4][64];
    sm[strip][l] = M; ssum[strip][l] = S;
    __syncthreads();
    if (strip == 0) {
        float Mf = fmaxf(fmaxf(sm[0][l], sm[1][l]), fmaxf(sm[2][l], sm[3][l]));
        float Sf = 0.0f;
        #pragma unroll
        for (int k = 0; k < 4; ++k)
            Sf += ssum[k][l] * __expf(sm[k][l] - Mf);
        float li = (Mf + logf(Sf)) - diag[R];
        #pragma unroll
        for (int off = 1; off < 64; off <<= 1) li += __shfl_xor(li, off, 64);
        if (l == 0) atomicAdd(out, li * (1.0f / (float)NB));
    }
}

extern "C" void kernel_launch(void* const* d_in, const int* in_sizes, int n_in,
                              void* d_out, int out_size, void* d_ws, size_t ws_size,
                              hipStream_t stream) {
    const float* q = (const float*)d_in[0];
    const float* p = (const float*)d_in[1];
    const float* n = (const float*)d_in[2];
    char* wsb = (char*)d_ws;
    // ws: Abf 8MB | Bbf 16MB | part_m 2MB | part_s 2MB | diag 16KB
    unsigned short* Abf = (unsigned short*)(wsb);
    unsigned short* Bbf = (unsigned short*)(wsb + ((size_t)8 << 20));
    float* part_m = (float*)(wsb + ((size_t)24 << 20));
    float* part_s = (float*)(wsb + ((size_t)26 << 20));
    float* diag   = (float*)(wsb + ((size_t)28 << 20));
    float* out = (float*)d_out;

    (void)hipFuncSetAttribute(reinterpret_cast<const void*>(&gemm_fused),
                              hipFuncAttributeMaxDynamicSharedMemorySize, 131072);

    hipMemsetAsync(out, 0, sizeof(float), stream);
    normalize_cast<<<3 * NB / 4, 256, 0, stream>>>(q, p, n, Abf, Bbf);
    gemm_fused<<<GEMM_GRID, 512, 131072, stream>>>(Abf, Bbf, part_m, part_s, diag);
    combine<<<NB / 64, 256, 0, stream>>>(part_m, part_s, diag, out);
}